// Round 6
// baseline (85.221 us; speedup 1.0000x reference)
//
#include <hip/hip_runtime.h>

typedef __attribute__((ext_vector_type(8))) short short8;
typedef __attribute__((ext_vector_type(16))) float f32x16;
typedef unsigned short ushort_t;

#define MFMA(A, B, C) __builtin_amdgcn_mfma_f32_32x32x16_bf16(A, B, C, 0, 0, 0)

__device__ __forceinline__ float4 ldf4(const float* p) { return *(const float4*)p; }
__device__ __forceinline__ short8 ld8(const void* p) { return *(const short8*)p; }

__device__ __forceinline__ short8 mk8(unsigned w0, unsigned w1, unsigned w2, unsigned w3) {
    union { unsigned u[4]; short8 s; } t;
    t.u[0] = w0; t.u[1] = w1; t.u[2] = w2; t.u[3] = w3;
    return t.s;
}
// pack bf16-truncations of (a,b): low16 = top16(a), high16 = top16(b)
__device__ __forceinline__ unsigned packhi2(float a, float b) {
    return __builtin_amdgcn_perm(__float_as_uint(b), __float_as_uint(a), 0x07060302u);
}
__device__ __forceinline__ float lopart(float v) {
    return v - __uint_as_float(__float_as_uint(v) & 0xFFFF0000u);
}
// v_permlane32_swap: lo' = [lo_lo, hi_lo], hi' = [lo_hi, hi_hi]
__device__ __forceinline__ void plswap(unsigned& lo, unsigned& hi) {
    asm("v_permlane32_swap_b32 %0, %1" : "+v"(lo), "+v"(hi));
}
__device__ __forceinline__ ushort_t h16(float x) { return (ushort_t)(__float_as_uint(x) >> 16); }
__device__ __forceinline__ float fh(ushort_t u) { return __uint_as_float(((unsigned)u) << 16); }

// ---------------- prepack ----------------
// w1t : [49 s][32 o][2 half][8 j] bf16 (hi only), rows>=20 zero. 50176 B.
// midt: [29 l][4 frag: A0h,A1h,A0l,A1l][64 lane=half*32+o][8 j] bf16 = 118784 B.
//   A1h j0..3 = W[o][16..19] (half0), j4 = bias_hi, j5 = bias_lo; A1l j0..3 = lo W[o][16..19].
//   layer 28 = fc30 (rows>=10 zero).
__global__ void prepack(const float* __restrict__ W1,
                        const float* __restrict__ Wmid, const float* __restrict__ bmid,
                        const float* __restrict__ W30, const float* __restrict__ b30,
                        ushort_t* __restrict__ w1t, ushort_t* __restrict__ midt)
{
    const int tid = blockIdx.x * 256 + threadIdx.x;
    const int nth = gridDim.x * 256;
    for (int i = tid; i < 49 * 512; i += nth) {
        const int j = i & 7, hf = (i >> 3) & 1, o = (i >> 4) & 31, s = i >> 9;
        const float v = (o < 20) ? W1[o * 784 + s * 16 + hf * 8 + j] : 0.f;
        w1t[i] = h16(v);
    }
    for (int e2 = tid; e2 < 29 * 64; e2 += nth) {
        const int ee = e2 & 63, l = e2 >> 6;
        const int o = ee & 31, hf = ee >> 5;
        ushort_t v[32];
#pragma unroll
        for (int i = 0; i < 32; ++i) v[i] = 0;
        const bool lastl = (l == 28);
        const int omax = lastl ? 10 : 20;
        if (o < omax) {
            const float* wr = lastl ? (W30 + o * 20) : (Wmid + l * 400 + o * 20);
            const float bias = lastl ? b30[o] : bmid[l * 20 + o];
#pragma unroll
            for (int j = 0; j < 8; ++j) {
                const float w = wr[hf * 8 + j];
                v[j]      = h16(w);
                v[16 + j] = h16(w - fh(h16(w)));
            }
            if (hf == 0) {
#pragma unroll
                for (int j = 0; j < 4; ++j) {
                    const float w = wr[16 + j];
                    v[8 + j]  = h16(w);
                    v[24 + j] = h16(w - fh(h16(w)));
                }
                v[12] = h16(bias);                   // A1h j4 (x B1h 1.0)
                v[13] = h16(bias - fh(h16(bias)));   // A1h j5 (x B1l 1.0)
            }
        }
#pragma unroll
        for (int f = 0; f < 4; ++f)
#pragma unroll
            for (int j = 0; j < 8; ++j)
                midt[l * 2048 + f * 512 + ee * 8 + j] = v[f * 8 + j];
    }
}

// ---------------- main ----------------
// Block = 4 waves, one 32-row tile. Stage x tile (contiguous 100 KB) coalesced ->
// bf16 LDS [32][792]; fc1 K-split 4-way (pages s = wv mod 4); LDS reduce (overlaid);
// wave0 runs the 29 prepacked mid/out layers in registers.
__global__ __launch_bounds__(256, 3)
void mlp_main(const float* __restrict__ x, const float* __restrict__ b1,
              const ushort_t* __restrict__ w1t, const ushort_t* __restrict__ midt,
              float* __restrict__ out, int nrows)
{
    __shared__ ushort_t xt[32 * 792];   // 50688 B; reduce buffer overlaid later

    const int tid  = threadIdx.x;
    const int lane = tid & 63;
    const int wv   = tid >> 6;
    const int r0   = blockIdx.x * 32;
    if (r0 >= nrows) return;
    const int colr = lane & 31;
    const int half = lane >> 5;
    const int row  = r0 + colr;

    // ---- stage: 6272 float4 linear, cvt bf16, LDS row-major padded ----
    const float4* xg = (const float4*)(x + (size_t)r0 * 784);
#define STG(IDX, V) do {                                                  \
        const unsigned _i = (unsigned)(IDX);                              \
        const unsigned _r = (_i * 10700u) >> 21;   /* /196 exact */       \
        const unsigned _c = _i - _r * 196u;                               \
        *(uint2*)&xt[_r * 792 + _c * 4] =                                 \
            make_uint2(packhi2((V).x, (V).y), packhi2((V).z, (V).w));     \
    } while (0)

#pragma unroll 1
    for (int i = 0; i < 24; i += 4) {
        const float4 v0 = xg[(i + 0) * 256 + tid];
        const float4 v1 = xg[(i + 1) * 256 + tid];
        const float4 v2 = xg[(i + 2) * 256 + tid];
        const float4 v3 = xg[(i + 3) * 256 + tid];
        STG((i + 0) * 256 + tid, v0);
        STG((i + 1) * 256 + tid, v1);
        STG((i + 2) * 256 + tid, v2);
        STG((i + 3) * 256 + tid, v3);
    }
    if (tid < 128) { const float4 v = xg[6144 + tid]; STG(6144 + tid, v); }
    __syncthreads();

    // ---- fc1: pages s = wv, wv+4, ... (w0 also takes s=48) ----
    f32x16 acc;
#pragma unroll
    for (int r = 0; r < 16; ++r) acc[r] = 0.f;
#pragma unroll 1
    for (int s = wv; s <= 48; s += 4) {
        const short8 A = ld8(w1t + s * 512 + colr * 16 + half * 8);
        const short8 B = ld8(&xt[colr * 792 + s * 16 + half * 8]);
        acc = MFMA(A, B, acc);
    }
    __syncthreads();

    // ---- cross-wave reduce (buffer overlaid on xt) ----
    float* red = (float*)xt;
    if (wv) {
#pragma unroll
        for (int r = 0; r < 16; ++r) red[(wv - 1) * 1024 + r * 64 + lane] = acc[r];
    }
    __syncthreads();
    if (wv) return;
#pragma unroll
    for (int r = 0; r < 16; ++r)
        acc[r] += (red[r * 64 + lane] + red[1024 + r * 64 + lane]) + red[2048 + r * 64 + lane];

    // bias + relu
    float Hv[16];
#pragma unroll
    for (int r = 0; r < 16; ++r) {
        const int o = (r & 3) + 8 * (r >> 2) + 4 * half;
        Hv[r] = fmaxf(acc[r] + b1[o < 20 ? o : 0], 0.f);
    }

    // ---- fc2..fc30: prepacked A hi/lo + bias-in-k, H hi/lo in registers ----
    const ushort_t* ap = midt + lane * 8;
#pragma unroll 1
    for (int l = 0; l < 29; ++l) {
        const short8 A0h = ld8(ap + l * 2048);
        const short8 A1h = ld8(ap + l * 2048 + 512);
        const short8 A0l = ld8(ap + l * 2048 + 1024);
        const short8 A1l = ld8(ap + l * 2048 + 1536);

        unsigned plo0 = packhi2(Hv[0], Hv[1]), plo1 = packhi2(Hv[2], Hv[3]);
        unsigned phi0 = packhi2(Hv[4], Hv[5]), phi1 = packhi2(Hv[6], Hv[7]);
        plswap(plo0, phi0); plswap(plo1, phi1);
        const short8 B0h = mk8(plo0, plo1, phi0, phi1);

        unsigned qlo0 = packhi2(lopart(Hv[0]), lopart(Hv[1]));
        unsigned qlo1 = packhi2(lopart(Hv[2]), lopart(Hv[3]));
        unsigned qhi0 = packhi2(lopart(Hv[4]), lopart(Hv[5]));
        unsigned qhi1 = packhi2(lopart(Hv[6]), lopart(Hv[7]));
        plswap(qlo0, qhi0); plswap(qlo1, qhi1);
        const short8 B0l = mk8(qlo0, qlo1, qhi0, qhi1);

        const short8 B1h = mk8(half ? 0u : packhi2(Hv[8], Hv[9]),
                               half ? 0u : packhi2(Hv[10], Hv[11]),
                               half ? 0u : 0x00003F80u, 0u);
        const short8 B1l = mk8(half ? 0u : packhi2(lopart(Hv[8]), lopart(Hv[9])),
                               half ? 0u : packhi2(lopart(Hv[10]), lopart(Hv[11])),
                               half ? 0u : 0x3F800000u, 0u);

        f32x16 d;
#pragma unroll
        for (int r = 0; r < 16; ++r) d[r] = 0.f;
        d = MFMA(A0h, B0h, d);
        d = MFMA(A0l, B0h, d);
        d = MFMA(A0h, B0l, d);
        d = MFMA(A1h, B1h, d);
        d = MFMA(A1l, B1h, d);
        d = MFMA(A1h, B1l, d);

        if (l < 28) {
#pragma unroll
            for (int r = 0; r < 16; ++r) Hv[r] = fmaxf(d[r], 0.f);
        } else {
#pragma unroll
            for (int r = 0; r < 16; ++r) {
                const int o = (r & 3) + 8 * (r >> 2) + 4 * half;
                if (o < 10) out[(size_t)row * 10 + o] = d[r];
            }
        }
    }
#undef STG
}

extern "C" void kernel_launch(void* const* d_in, const int* in_sizes, int n_in,
                              void* d_out, int out_size, void* d_ws, size_t ws_size,
                              hipStream_t stream)
{
    const float* x    = (const float*)d_in[0];
    const float* W1   = (const float*)d_in[1];
    const float* b1   = (const float*)d_in[2];
    const float* Wmid = (const float*)d_in[3];
    const float* bmid = (const float*)d_in[4];
    const float* W30  = (const float*)d_in[5];
    const float* b30  = (const float*)d_in[6];
    float* out = (float*)d_out;

    ushort_t* w1t  = (ushort_t*)d_ws;                       // 50176 B
    ushort_t* midt = (ushort_t*)((char*)d_ws + 50176);      // 118784 B

    const int nrows = in_sizes[0] / 784;
    prepack<<<32, 256, 0, stream>>>(W1, Wmid, bmid, W30, b30, w1t, midt);
    const int grid = (nrows + 31) / 32;    // 2048 blocks, 1 tile each
    mlp_main<<<grid, 256, 0, stream>>>(x, b1, w1t, midt, out, nrows);
}

// Round 7
// 72.370 us; speedup vs baseline: 1.1776x; 1.1776x over previous
//
#include <hip/hip_runtime.h>

typedef __attribute__((ext_vector_type(8))) short short8;
typedef __attribute__((ext_vector_type(16))) float f32x16;
typedef unsigned short ushort_t;

#define MFMA(A, B, C) __builtin_amdgcn_mfma_f32_32x32x16_bf16(A, B, C, 0, 0, 0)

__device__ __forceinline__ float4 ldf4(const float* p) { return *(const float4*)p; }
__device__ __forceinline__ short8 ld8(const void* p) { return *(const short8*)p; }

__device__ __forceinline__ short8 mk8(unsigned w0, unsigned w1, unsigned w2, unsigned w3) {
    union { unsigned u[4]; short8 s; } t;
    t.u[0] = w0; t.u[1] = w1; t.u[2] = w2; t.u[3] = w3;
    return t.s;
}
// pack bf16-truncations of (a,b): low16 = top16(a), high16 = top16(b)
__device__ __forceinline__ unsigned packhi2(float a, float b) {
    return __builtin_amdgcn_perm(__float_as_uint(b), __float_as_uint(a), 0x07060302u);
}
__device__ __forceinline__ float lopart(float v) {
    return v - __uint_as_float(__float_as_uint(v) & 0xFFFF0000u);
}
// v_permlane32_swap: lo' = [lo_lo, hi_lo], hi' = [lo_hi, hi_hi]
__device__ __forceinline__ void plswap(unsigned& lo, unsigned& hi) {
    asm("v_permlane32_swap_b32 %0, %1" : "+v"(lo), "+v"(hi));
}
__device__ __forceinline__ ushort_t h16(float x) { return (ushort_t)(__float_as_uint(x) >> 16); }
__device__ __forceinline__ float fh(ushort_t u) { return __uint_as_float(((unsigned)u) << 16); }

// ---------------- prepack (unchanged layouts from R6, both proven) ----------------
// w1t : [49 s][32 o][2 half][8 j] bf16 (hi only), rows>=20 zero. 50176 B.
// midt: [29 l][4 frag: A0h,A1h,A0l,A1l][64 lane=half*32+o][8 j] bf16 = 118784 B.
__global__ void prepack(const float* __restrict__ W1,
                        const float* __restrict__ Wmid, const float* __restrict__ bmid,
                        const float* __restrict__ W30, const float* __restrict__ b30,
                        ushort_t* __restrict__ w1t, ushort_t* __restrict__ midt)
{
    const int tid = blockIdx.x * 256 + threadIdx.x;
    const int nth = gridDim.x * 256;
    for (int i = tid; i < 49 * 512; i += nth) {
        const int j = i & 7, hf = (i >> 3) & 1, o = (i >> 4) & 31, s = i >> 9;
        const float v = (o < 20) ? W1[o * 784 + s * 16 + hf * 8 + j] : 0.f;
        w1t[i] = h16(v);
    }
    for (int e2 = tid; e2 < 29 * 64; e2 += nth) {
        const int ee = e2 & 63, l = e2 >> 6;
        const int o = ee & 31, hf = ee >> 5;
        ushort_t v[32];
#pragma unroll
        for (int i = 0; i < 32; ++i) v[i] = 0;
        const bool lastl = (l == 28);
        const int omax = lastl ? 10 : 20;
        if (o < omax) {
            const float* wr = lastl ? (W30 + o * 20) : (Wmid + l * 400 + o * 20);
            const float bias = lastl ? b30[o] : bmid[l * 20 + o];
#pragma unroll
            for (int j = 0; j < 8; ++j) {
                const float w = wr[hf * 8 + j];
                v[j]      = h16(w);
                v[16 + j] = h16(w - fh(h16(w)));
            }
            if (hf == 0) {
#pragma unroll
                for (int j = 0; j < 4; ++j) {
                    const float w = wr[16 + j];
                    v[8 + j]  = h16(w);
                    v[24 + j] = h16(w - fh(h16(w)));
                }
                v[12] = h16(bias);                   // A1h j4 (x B1h k20=1.0)
                v[13] = h16(bias - fh(h16(bias)));   // A1h j5 (x B1l k21=1.0)
            }
        }
#pragma unroll
        for (int f = 0; f < 4; ++f)
#pragma unroll
            for (int j = 0; j < 8; ++j)
                midt[l * 2048 + f * 512 + ee * 8 + j] = v[f * 8 + j];
    }
}

// ---------------- K1: fc1 only ----------------
// Block = 4 waves, 64 rows (2 tiles of 32). Wave w: tile t=w&1, k-part p=w>>1.
// x staged coalesced in 2 phases (cols 0..399 / 400..783) into LDS [64][404] bf16.
// H stored RAW in fragment layout: Hws[(gtile*64+lane)*16 + r] (coalesced f32x16).
__global__ __launch_bounds__(256, 3)
void mlp_fc1(const float* __restrict__ x, const float* __restrict__ b1,
             const ushort_t* __restrict__ w1t, float* __restrict__ Hws, int nrows)
{
    __shared__ ushort_t xt[64 * 404];   // 51712 B -> 3 blocks/CU

    const int tid  = threadIdx.x;
    const int lane = tid & 63;
    const int wv   = tid >> 6;
    const int t    = wv & 1;
    const int kp   = wv >> 1;
    const int r0   = blockIdx.x * 64;
    if (r0 >= nrows) return;
    const int colr = lane & 31;
    const int half = lane >> 5;

    f32x16 acc;
#pragma unroll
    for (int r = 0; r < 16; ++r) acc[r] = 0.f;

    const float* xb = x + (size_t)r0 * 784;

#pragma unroll 1
    for (int ph = 0; ph < 2; ++ph) {
        // ---- coalesced stage: ph0 = 100 f4/row (cols 0..399), ph1 = 96 (400..783)
        if (ph == 0) {
#pragma unroll 1
            for (int b = 0; b < 5; ++b) {
                float4 v[5]; unsigned rr[5], cc[5];
#pragma unroll
                for (int u = 0; u < 5; ++u) {
                    const unsigned i = (b * 5 + u) * 256 + tid;      // < 6400
                    unsigned r = i / 100u, c = i - r * 100u;
                    unsigned gr = r0 + r < (unsigned)nrows ? r : (unsigned)(nrows - 1 - r0);
                    rr[u] = r; cc[u] = c;
                    v[u] = ldf4(xb + (size_t)gr * 784 + c * 4);
                }
#pragma unroll
                for (int u = 0; u < 5; ++u)
                    *(uint2*)&xt[rr[u] * 404 + cc[u] * 4] =
                        make_uint2(packhi2(v[u].x, v[u].y), packhi2(v[u].z, v[u].w));
            }
        } else {
#pragma unroll 1
            for (int b = 0; b < 4; ++b) {
                float4 v[6]; unsigned rr[6], cc[6];
#pragma unroll
                for (int u = 0; u < 6; ++u) {
                    const unsigned i = (b * 6 + u) * 256 + tid;      // < 6144
                    unsigned r = i / 96u, c = i - r * 96u;
                    unsigned gr = r0 + r < (unsigned)nrows ? r : (unsigned)(nrows - 1 - r0);
                    rr[u] = r; cc[u] = c;
                    v[u] = ldf4(xb + (size_t)gr * 784 + 400 + c * 4);
                }
#pragma unroll
                for (int u = 0; u < 6; ++u)
                    *(uint2*)&xt[rr[u] * 404 + cc[u] * 4] =
                        make_uint2(packhi2(v[u].x, v[u].y), packhi2(v[u].z, v[u].w));
            }
        }
        __syncthreads();

        // ---- compute this phase's steps (k-split across wave pairs)
        const int nst = ph ? 24 : 25;
        const int lo  = kp ? (ph ? 12 : 13) : 0;
        const int hi  = kp ? nst : (ph ? 12 : 13);
        const int sgb = ph * 25;
#pragma unroll 1
        for (int s = lo; s < hi; ++s) {
            const short8 A = ld8(w1t + (sgb + s) * 512 + colr * 16 + half * 8);
            const short8 B = ld8(&xt[(t * 32 + colr) * 404 + s * 16 + half * 8]);
            acc = MFMA(A, B, acc);
        }
        __syncthreads();
    }

    // ---- cross-pair reduce via LDS (overlaid on xt) ----
    float* red = (float*)xt;
    if (kp) {
#pragma unroll
        for (int r = 0; r < 16; ++r) red[t * 1024 + r * 64 + lane] = acc[r];
    }
    __syncthreads();
    if (kp) return;

    float Hv[16];
#pragma unroll
    for (int r = 0; r < 16; ++r) {
        const int o = (r & 3) + 8 * (r >> 2) + 4 * half;
        Hv[r] = fmaxf(acc[r] + red[t * 1024 + r * 64 + lane] + b1[o < 20 ? o : 0], 0.f);
    }

    float4* dst = (float4*)(Hws + ((size_t)(blockIdx.x * 2 + t) * 64 + lane) * 16);
    dst[0] = *(float4*)&Hv[0];
    dst[1] = *(float4*)&Hv[4];
    dst[2] = *(float4*)&Hv[8];
    dst[3] = *(float4*)&Hv[12];
}

// ---------------- K2: fc2..fc30, one independent wave per 32-row tile ----------------
__global__ __launch_bounds__(256, 2)
void mlp_mid(const float* __restrict__ Hws, const ushort_t* __restrict__ midt,
             float* __restrict__ out, int ntiles, int nrows)
{
    const int lane = threadIdx.x & 63;
    const int wv   = threadIdx.x >> 6;
    const int tile = blockIdx.x * 4 + wv;
    if (tile >= ntiles) return;
    const int colr = lane & 31;
    const int half = lane >> 5;
    const int row  = tile * 32 + colr;

    float Hv[16];
    const float4* src = (const float4*)(Hws + ((size_t)tile * 64 + lane) * 16);
    *(float4*)&Hv[0]  = src[0];
    *(float4*)&Hv[4]  = src[1];
    *(float4*)&Hv[8]  = src[2];
    *(float4*)&Hv[12] = src[3];

    const ushort_t* ap = midt + lane * 8;
#pragma unroll 1
    for (int l = 0; l < 29; ++l) {
        const short8 A0h = ld8(ap + l * 2048);
        const short8 A1h = ld8(ap + l * 2048 + 512);
        const short8 A0l = ld8(ap + l * 2048 + 1024);
        const short8 A1l = ld8(ap + l * 2048 + 1536);

        unsigned plo0 = packhi2(Hv[0], Hv[1]), plo1 = packhi2(Hv[2], Hv[3]);
        unsigned phi0 = packhi2(Hv[4], Hv[5]), phi1 = packhi2(Hv[6], Hv[7]);
        plswap(plo0, phi0); plswap(plo1, phi1);
        const short8 B0h = mk8(plo0, plo1, phi0, phi1);

        unsigned qlo0 = packhi2(lopart(Hv[0]), lopart(Hv[1]));
        unsigned qlo1 = packhi2(lopart(Hv[2]), lopart(Hv[3]));
        unsigned qhi0 = packhi2(lopart(Hv[4]), lopart(Hv[5]));
        unsigned qhi1 = packhi2(lopart(Hv[6]), lopart(Hv[7]));
        plswap(qlo0, qhi0); plswap(qlo1, qhi1);
        const short8 B0l = mk8(qlo0, qlo1, qhi0, qhi1);

        const short8 B1h = mk8(half ? 0u : packhi2(Hv[8], Hv[9]),
                               half ? 0u : packhi2(Hv[10], Hv[11]),
                               half ? 0u : 0x00003F80u, 0u);
        const short8 B1l = mk8(half ? 0u : packhi2(lopart(Hv[8]), lopart(Hv[9])),
                               half ? 0u : packhi2(lopart(Hv[10]), lopart(Hv[11])),
                               half ? 0u : 0x3F800000u, 0u);

        f32x16 d;
#pragma unroll
        for (int r = 0; r < 16; ++r) d[r] = 0.f;
        d = MFMA(A0h, B0h, d);
        d = MFMA(A0l, B0h, d);
        d = MFMA(A0h, B0l, d);
        d = MFMA(A1h, B1h, d);
        d = MFMA(A1l, B1h, d);
        d = MFMA(A1h, B1l, d);

        if (l < 28) {
#pragma unroll
            for (int r = 0; r < 16; ++r) Hv[r] = fmaxf(d[r], 0.f);
        } else {
            if (row < nrows) {
#pragma unroll
                for (int r = 0; r < 16; ++r) {
                    const int o = (r & 3) + 8 * (r >> 2) + 4 * half;
                    if (o < 10) out[(size_t)row * 10 + o] = d[r];
                }
            }
        }
    }
}

extern "C" void kernel_launch(void* const* d_in, const int* in_sizes, int n_in,
                              void* d_out, int out_size, void* d_ws, size_t ws_size,
                              hipStream_t stream)
{
    const float* x    = (const float*)d_in[0];
    const float* W1   = (const float*)d_in[1];
    const float* b1   = (const float*)d_in[2];
    const float* Wmid = (const float*)d_in[3];
    const float* bmid = (const float*)d_in[4];
    const float* W30  = (const float*)d_in[5];
    const float* b30  = (const float*)d_in[6];
    float* out = (float*)d_out;

    ushort_t* w1t  = (ushort_t*)d_ws;                       // 50176 B
    ushort_t* midt = (ushort_t*)((char*)d_ws + 50176);      // 118784 B
    float*    Hws  = (float*)((char*)d_ws + 169984);        // 2048*64*16*4 = 8.4 MB

    const int nrows  = in_sizes[0] / 784;
    const int ntiles = (nrows + 31) / 32;                   // 2048
    prepack<<<32, 256, 0, stream>>>(W1, Wmid, bmid, W30, b30, w1t, midt);
    mlp_fc1<<<(nrows + 63) / 64, 256, 0, stream>>>(x, b1, w1t, Hws, nrows);
    mlp_mid<<<(ntiles + 3) / 4, 256, 0, stream>>>(Hws, midt, out, ntiles, nrows);
}

// Round 8
// 52.634 us; speedup vs baseline: 1.6191x; 1.3750x over previous
//
#include <hip/hip_runtime.h>

typedef __attribute__((ext_vector_type(8))) short short8;
typedef __attribute__((ext_vector_type(16))) float f32x16;
typedef unsigned short ushort_t;

#define MFMA(A, B, C) __builtin_amdgcn_mfma_f32_32x32x16_bf16(A, B, C, 0, 0, 0)

__device__ __forceinline__ float4 ldf4(const float* p) { return *(const float4*)p; }
__device__ __forceinline__ short8 ld8(const void* p) { return *(const short8*)p; }

__device__ __forceinline__ short8 mk8(unsigned w0, unsigned w1, unsigned w2, unsigned w3) {
    union { unsigned u[4]; short8 s; } t;
    t.u[0] = w0; t.u[1] = w1; t.u[2] = w2; t.u[3] = w3;
    return t.s;
}
// pack bf16-truncations of (a,b): low16 = top16(a), high16 = top16(b)
__device__ __forceinline__ unsigned packhi2(float a, float b) {
    return __builtin_amdgcn_perm(__float_as_uint(b), __float_as_uint(a), 0x07060302u);
}
__device__ __forceinline__ float lopart(float v) {
    return v - __uint_as_float(__float_as_uint(v) & 0xFFFF0000u);
}
// v_permlane32_swap: lo' = [lo_lo, hi_lo], hi' = [lo_hi, hi_hi]
__device__ __forceinline__ void plswap(unsigned& lo, unsigned& hi) {
    asm("v_permlane32_swap_b32 %0, %1" : "+v"(lo), "+v"(hi));
}
__device__ __forceinline__ ushort_t h16(float x) { return (ushort_t)(__float_as_uint(x) >> 16); }
__device__ __forceinline__ float fh(ushort_t u) { return __uint_as_float(((unsigned)u) << 16); }

// async global->LDS, 16 B per lane; lds base wave-uniform, gsrc per-lane
__device__ __forceinline__ void dma16(const float* g, void* l) {
    __builtin_amdgcn_global_load_lds((const __attribute__((address_space(1))) void*)g,
                                     (__attribute__((address_space(3))) void*)l, 16, 0, 0);
}

// ---------------- prepack (layouts proven in R5-R7) ----------------
// w1t : [49 s][32 o][2 half][8 j] bf16 (hi only), rows>=20 zero. 50176 B.
// midt: [29 l][4 frag: A0h,A1h,A0l,A1l][64 lane=half*32+o][8 j] bf16 = 118784 B.
__global__ void prepack(const float* __restrict__ W1,
                        const float* __restrict__ Wmid, const float* __restrict__ bmid,
                        const float* __restrict__ W30, const float* __restrict__ b30,
                        ushort_t* __restrict__ w1t, ushort_t* __restrict__ midt)
{
    const int tid = blockIdx.x * 256 + threadIdx.x;
    const int nth = gridDim.x * 256;
    for (int i = tid; i < 49 * 512; i += nth) {
        const int j = i & 7, hf = (i >> 3) & 1, o = (i >> 4) & 31, s = i >> 9;
        const float v = (o < 20) ? W1[o * 784 + s * 16 + hf * 8 + j] : 0.f;
        w1t[i] = h16(v);
    }
    for (int e2 = tid; e2 < 29 * 64; e2 += nth) {
        const int ee = e2 & 63, l = e2 >> 6;
        const int o = ee & 31, hf = ee >> 5;
        ushort_t v[32];
#pragma unroll
        for (int i = 0; i < 32; ++i) v[i] = 0;
        const bool lastl = (l == 28);
        const int omax = lastl ? 10 : 20;
        if (o < omax) {
            const float* wr = lastl ? (W30 + o * 20) : (Wmid + l * 400 + o * 20);
            const float bias = lastl ? b30[o] : bmid[l * 20 + o];
#pragma unroll
            for (int j = 0; j < 8; ++j) {
                const float w = wr[hf * 8 + j];
                v[j]      = h16(w);
                v[16 + j] = h16(w - fh(h16(w)));
            }
            if (hf == 0) {
#pragma unroll
                for (int j = 0; j < 4; ++j) {
                    const float w = wr[16 + j];
                    v[8 + j]  = h16(w);
                    v[24 + j] = h16(w - fh(h16(w)));
                }
                v[12] = h16(bias);                   // A1h j4 (x B1h k20=1.0)
                v[13] = h16(bias - fh(h16(bias)));   // A1h j5 (x B1l k21=1.0)
            }
        }
#pragma unroll
        for (int f = 0; f < 4; ++f)
#pragma unroll
            for (int j = 0; j < 8; ++j)
                midt[l * 2048 + f * 512 + ee * 8 + j] = v[f * 8 + j];
    }
}

// ---------------- fused main ----------------
// Block = 4 waves, 128 rows; wave wv owns rows [wv*32, wv*32+32).
// fc1: 12 phases x 64 cols, fp32 x DMA'd into double-buffered LDS (32 KB each),
// XOR-swizzled 16B units (g ^ (row&7)); counted vmcnt(8) keeps next phase's DMAs
// in flight across raw barriers. Tail (cols 768..783) staged once at start.
// Then each wave independently runs fc2..fc30 in registers (proven path).
__global__ __launch_bounds__(256, 2)
void mlp_main(const float* __restrict__ x, const float* __restrict__ b1,
              const ushort_t* __restrict__ w1t, const ushort_t* __restrict__ midt,
              float* __restrict__ out, int nrows)
{
    __shared__ float xt[2][8192];     // 2 x 32 KB: [128 rows][16 units][4 floats]
    __shared__ float xtail[2048];     // 8 KB: [128 rows][4 units][4 floats]

    const int tid  = threadIdx.x;
    const int lane = tid & 63;
    const int wv   = tid >> 6;
    const int r0   = blockIdx.x * 128;
    if (r0 >= nrows) return;
    const int colr = lane & 31;
    const int half = lane >> 5;
    const int rowl = wv * 32 + colr;          // row within block (this wave's tile)
    const int rsw  = rowl & 7;                // swizzle key for reads
    const int row  = r0 + rowl;               // global batch row

#define ISSUE_PHASE(PH, BUF) do {                                          \
        char* _lb = (char*)&xt[(BUF)][0] + (wv * 8) * 1024;                \
        const int _pc = (PH) * 64;                                         \
        _Pragma("unroll")                                                  \
        for (int k = 0; k < 8; ++k) {                                      \
            const int slot = (wv * 8 + k) * 64 + lane;                     \
            const int r = slot >> 4, gs = slot & 15;                       \
            const int g = gs ^ (r & 7);                                    \
            const size_t gr = (size_t)((r0 + r < nrows) ? (r0 + r) : (nrows - 1)); \
            dma16(x + gr * 784 + _pc + g * 4, _lb + k * 1024);             \
        }                                                                  \
    } while (0)

    // ---- prologue: issue tail (cols 768..783) then phase 0 ----
#pragma unroll
    for (int k = 0; k < 2; ++k) {
        const int slot = (wv * 2 + k) * 64 + lane;        // 0..511
        const int r = slot >> 2, u = slot & 3;
        const size_t gr = (size_t)((r0 + r < nrows) ? (r0 + r) : (nrows - 1));
        dma16(x + gr * 784 + 768 + u * 4, (char*)xtail + (wv * 2 + k) * 1024);
    }
    ISSUE_PHASE(0, 0);

    f32x16 acc;
#pragma unroll
    for (int r = 0; r < 16; ++r) acc[r] = 0.f;

    // ---- 12 pipelined phases ----
#pragma unroll 1
    for (int p = 0; p < 12; ++p) {
        // A-fragment prefetch for this phase (issued before next DMA batch)
        const ushort_t* ab = w1t + (p * 4) * 512 + colr * 16 + half * 8;
        const short8 A0 = ld8(ab);
        const short8 A1 = ld8(ab + 512);
        const short8 A2 = ld8(ab + 1024);
        const short8 A3 = ld8(ab + 1536);

        if (p < 11) {
            ISSUE_PHASE(p + 1, (p + 1) & 1);
            // wait: this phase's 8 DMAs + 4 A-loads done; next phase's 8 stay in flight
            asm volatile("s_waitcnt vmcnt(8)" ::: "memory");
        } else {
            asm volatile("s_waitcnt vmcnt(0)" ::: "memory");
        }
        __builtin_amdgcn_sched_barrier(0);
        asm volatile("s_barrier" ::: "memory");   // collective: phase p data in LDS
        __builtin_amdgcn_sched_barrier(0);

        const float* xl = &xt[p & 1][0];
#pragma unroll
        for (int s = 0; s < 4; ++s) {
            const int g = s * 4 + half * 2;
            const float4 va = *(const float4*)&xl[(rowl * 16 + (g ^ rsw)) * 4];
            const float4 vb = *(const float4*)&xl[(rowl * 16 + ((g + 1) ^ rsw)) * 4];
            const short8 B = mk8(packhi2(va.x, va.y), packhi2(va.z, va.w),
                                 packhi2(vb.x, vb.y), packhi2(vb.z, vb.w));
            acc = MFMA(s == 0 ? A0 : s == 1 ? A1 : s == 2 ? A2 : A3, B, acc);
        }
        asm volatile("s_barrier" ::: "memory");   // protect buffer from next overwrite
    }

    // ---- tail step: cols 768..783 (staged at prologue, long since drained) ----
    {
        const short8 At = ld8(w1t + 48 * 512 + colr * 16 + half * 8);
        const float4 va = *(const float4*)&xtail[(rowl * 4 + half * 2) * 4];
        const float4 vb = *(const float4*)&xtail[(rowl * 4 + half * 2 + 1) * 4];
        const short8 B = mk8(packhi2(va.x, va.y), packhi2(va.z, va.w),
                             packhi2(vb.x, vb.y), packhi2(vb.z, vb.w));
        acc = MFMA(At, B, acc);
    }

    // ---- bias + relu (pad rows o>=20 get acc=0 from zeroed w1t rows) ----
    float Hv[16];
#pragma unroll
    for (int r = 0; r < 16; ++r) {
        const int o = (r & 3) + 8 * (r >> 2) + 4 * half;
        Hv[r] = fmaxf(acc[r] + b1[o < 20 ? o : 0], 0.f);
    }

    // ---- fc2..fc30: prepacked A hi/lo + bias-in-k, H hi/lo (proven) ----
    const ushort_t* ap = midt + lane * 8;
#pragma unroll 1
    for (int l = 0; l < 29; ++l) {
        const short8 A0h = ld8(ap + l * 2048);
        const short8 A1h = ld8(ap + l * 2048 + 512);
        const short8 A0l = ld8(ap + l * 2048 + 1024);
        const short8 A1l = ld8(ap + l * 2048 + 1536);

        unsigned plo0 = packhi2(Hv[0], Hv[1]), plo1 = packhi2(Hv[2], Hv[3]);
        unsigned phi0 = packhi2(Hv[4], Hv[5]), phi1 = packhi2(Hv[6], Hv[7]);
        plswap(plo0, phi0); plswap(plo1, phi1);
        const short8 B0h = mk8(plo0, plo1, phi0, phi1);

        unsigned qlo0 = packhi2(lopart(Hv[0]), lopart(Hv[1]));
        unsigned qlo1 = packhi2(lopart(Hv[2]), lopart(Hv[3]));
        unsigned qhi0 = packhi2(lopart(Hv[4]), lopart(Hv[5]));
        unsigned qhi1 = packhi2(lopart(Hv[6]), lopart(Hv[7]));
        plswap(qlo0, qhi0); plswap(qlo1, qhi1);
        const short8 B0l = mk8(qlo0, qlo1, qhi0, qhi1);

        const short8 B1h = mk8(half ? 0u : packhi2(Hv[8], Hv[9]),
                               half ? 0u : packhi2(Hv[10], Hv[11]),
                               half ? 0u : 0x00003F80u, 0u);
        const short8 B1l = mk8(half ? 0u : packhi2(lopart(Hv[8]), lopart(Hv[9])),
                               half ? 0u : packhi2(lopart(Hv[10]), lopart(Hv[11])),
                               half ? 0u : 0x3F800000u, 0u);

        f32x16 d;
#pragma unroll
        for (int r = 0; r < 16; ++r) d[r] = 0.f;
        d = MFMA(A0h, B0h, d);
        d = MFMA(A0l, B0h, d);
        d = MFMA(A0h, B0l, d);
        d = MFMA(A1h, B1h, d);
        d = MFMA(A1l, B1h, d);
        d = MFMA(A1h, B1l, d);

        if (l < 28) {
#pragma unroll
            for (int r = 0; r < 16; ++r) Hv[r] = fmaxf(d[r], 0.f);
        } else {
            if (row < nrows) {
#pragma unroll
                for (int r = 0; r < 16; ++r) {
                    const int o = (r & 3) + 8 * (r >> 2) + 4 * half;
                    if (o < 10) out[(size_t)row * 10 + o] = d[r];
                }
            }
        }
    }
#undef ISSUE_PHASE
}

extern "C" void kernel_launch(void* const* d_in, const int* in_sizes, int n_in,
                              void* d_out, int out_size, void* d_ws, size_t ws_size,
                              hipStream_t stream)
{
    const float* x    = (const float*)d_in[0];
    const float* W1   = (const float*)d_in[1];
    const float* b1   = (const float*)d_in[2];
    const float* Wmid = (const float*)d_in[3];
    const float* bmid = (const float*)d_in[4];
    const float* W30  = (const float*)d_in[5];
    const float* b30  = (const float*)d_in[6];
    float* out = (float*)d_out;

    ushort_t* w1t  = (ushort_t*)d_ws;                       // 50176 B
    ushort_t* midt = (ushort_t*)((char*)d_ws + 50176);      // 118784 B

    const int nrows = in_sizes[0] / 784;
    prepack<<<32, 256, 0, stream>>>(W1, Wmid, bmid, W30, b30, w1t, midt);
    const int grid = (nrows + 127) / 128;                   // 512 blocks, 2/CU
    mlp_main<<<grid, 256, 0, stream>>>(x, b1, w1t, midt, out, nrows);
}

// Round 9
// 52.072 us; speedup vs baseline: 1.6366x; 1.0108x over previous
//
#include <hip/hip_runtime.h>

typedef __attribute__((ext_vector_type(8))) short short8;
typedef __attribute__((ext_vector_type(16))) float f32x16;
typedef unsigned short ushort_t;

#define MFMA(A, B, C) __builtin_amdgcn_mfma_f32_32x32x16_bf16(A, B, C, 0, 0, 0)

__device__ __forceinline__ float4 ldf4(const float* p) { return *(const float4*)p; }
__device__ __forceinline__ short8 ld8(const void* p) { return *(const short8*)p; }

__device__ __forceinline__ short8 mk8(unsigned w0, unsigned w1, unsigned w2, unsigned w3) {
    union { unsigned u[4]; short8 s; } t;
    t.u[0] = w0; t.u[1] = w1; t.u[2] = w2; t.u[3] = w3;
    return t.s;
}
// pack bf16-truncations of (a,b): low16 = top16(a), high16 = top16(b)
__device__ __forceinline__ unsigned packhi2(float a, float b) {
    return __builtin_amdgcn_perm(__float_as_uint(b), __float_as_uint(a), 0x07060302u);
}
__device__ __forceinline__ float lopart(float v) {
    return v - __uint_as_float(__float_as_uint(v) & 0xFFFF0000u);
}
// v_permlane32_swap: lo' = [lo_lo, hi_lo], hi' = [lo_hi, hi_hi]
__device__ __forceinline__ void plswap(unsigned& lo, unsigned& hi) {
    asm("v_permlane32_swap_b32 %0, %1" : "+v"(lo), "+v"(hi));
}
__device__ __forceinline__ ushort_t h16(float x) { return (ushort_t)(__float_as_uint(x) >> 16); }
__device__ __forceinline__ float fh(ushort_t u) { return __uint_as_float(((unsigned)u) << 16); }

// async global->LDS, 16 B per lane; lds base wave-uniform, gsrc per-lane
__device__ __forceinline__ void dma16(const float* g, void* l) {
    __builtin_amdgcn_global_load_lds((const __attribute__((address_space(1))) void*)g,
                                     (__attribute__((address_space(3))) void*)l, 16, 0, 0);
}

// ---------------- prepack (layouts proven R5-R8) ----------------
// w1t : [49 s][32 o][2 half][8 j] bf16 (hi only), rows>=20 zero. 50176 B.
// midt: [29 l][4 frag: A0h,A1h,A0l,A1l][64 lane=half*32+o][8 j] bf16 = 118784 B.
__global__ void prepack(const float* __restrict__ W1,
                        const float* __restrict__ Wmid, const float* __restrict__ bmid,
                        const float* __restrict__ W30, const float* __restrict__ b30,
                        ushort_t* __restrict__ w1t, ushort_t* __restrict__ midt)
{
    const int tid = blockIdx.x * 256 + threadIdx.x;
    const int nth = gridDim.x * 256;
    for (int i = tid; i < 49 * 512; i += nth) {
        const int j = i & 7, hf = (i >> 3) & 1, o = (i >> 4) & 31, s = i >> 9;
        const float v = (o < 20) ? W1[o * 784 + s * 16 + hf * 8 + j] : 0.f;
        w1t[i] = h16(v);
    }
    for (int e2 = tid; e2 < 29 * 64; e2 += nth) {
        const int ee = e2 & 63, l = e2 >> 6;
        const int o = ee & 31, hf = ee >> 5;
        ushort_t v[32];
#pragma unroll
        for (int i = 0; i < 32; ++i) v[i] = 0;
        const bool lastl = (l == 28);
        const int omax = lastl ? 10 : 20;
        if (o < omax) {
            const float* wr = lastl ? (W30 + o * 20) : (Wmid + l * 400 + o * 20);
            const float bias = lastl ? b30[o] : bmid[l * 20 + o];
#pragma unroll
            for (int j = 0; j < 8; ++j) {
                const float w = wr[hf * 8 + j];
                v[j]      = h16(w);
                v[16 + j] = h16(w - fh(h16(w)));
            }
            if (hf == 0) {
#pragma unroll
                for (int j = 0; j < 4; ++j) {
                    const float w = wr[16 + j];
                    v[8 + j]  = h16(w);
                    v[24 + j] = h16(w - fh(h16(w)));
                }
                v[12] = h16(bias);                   // A1h j4 (x B1h k20=1.0)
                v[13] = h16(bias - fh(h16(bias)));   // A1h j5 (x B1l k21=1.0)
            }
        }
#pragma unroll
        for (int f = 0; f < 4; ++f)
#pragma unroll
            for (int j = 0; j < 8; ++j)
                midt[l * 2048 + f * 512 + ee * 8 + j] = v[f * 8 + j];
    }
}

// ---------------- fused main: barrier-free per-wave pipeline ----------------
// Block = 4 waves, 128 rows; wave wv owns rows [wv*32, wv*32+32) and a PRIVATE
// double-buffered LDS slice (2 x 4 KB, 32-col phases) + private 2 KB tail slice.
// No s_barrier anywhere: WAR hazard covered by program order (ds_read data is
// consumed behind lgkmcnt(0) before the next DMA issue), RAW by counted vmcnt(4).
// 24 phases x 32 cols + 16-col tail. DMA source pre-swizzled gs^(rl&7), read
// applies the same XOR (involution). K-order identical to R8 -> bit-identical.
__global__ __launch_bounds__(256, 4)
void mlp_main(const float* __restrict__ x, const float* __restrict__ b1,
              const ushort_t* __restrict__ w1t, const ushort_t* __restrict__ midt,
              float* __restrict__ out, int nrows)
{
    __shared__ float xt[2][4096];     // 2 x 16 KB: per wave 4 KB = [32 rows][8 units][4 f]
    __shared__ float xtail[2048];     // 8 KB: per wave 2 KB = [32 rows][4 units][4 f]

    const int tid  = threadIdx.x;
    const int lane = tid & 63;
    const int wv   = tid >> 6;
    const int r0   = blockIdx.x * 128;
    if (r0 >= nrows) return;
    const int colr = lane & 31;
    const int half = lane >> 5;
    const int rsw  = colr & 7;                // swizzle key for reads
    const int row  = r0 + wv * 32 + colr;     // global batch row
    const int rw0  = r0 + wv * 32;            // wave's first row

#define ISSUE_PHASE(PH, BUF) do {                                          \
        char* _lb = (char*)&xt[(BUF)][wv * 1024];                          \
        const int _pc = (PH) * 32;                                         \
        _Pragma("unroll")                                                  \
        for (int k = 0; k < 4; ++k) {                                      \
            const int slot = k * 64 + lane;          /* 0..255 */          \
            const int rl = slot >> 3, gs = slot & 7;                       \
            const int g = gs ^ (rl & 7);                                   \
            const size_t gr = (size_t)((rw0 + rl < nrows) ? (rw0 + rl) : (nrows - 1)); \
            dma16(x + gr * 784 + _pc + g * 4, _lb + k * 1024);             \
        }                                                                  \
    } while (0)

    // ---- prologue: tail (cols 768..783, own rows) then phase 0 ----
#pragma unroll
    for (int k = 0; k < 2; ++k) {
        const int slot = k * 64 + lane;               // 0..127
        const int rl = slot >> 2, u = slot & 3;
        const size_t gr = (size_t)((rw0 + rl < nrows) ? (rw0 + rl) : (nrows - 1));
        dma16(x + gr * 784 + 768 + u * 4, (char*)xtail + wv * 2048 + k * 1024);
    }
    ISSUE_PHASE(0, 0);

    f32x16 acc;
#pragma unroll
    for (int r = 0; r < 16; ++r) acc[r] = 0.f;

    // ---- 24 pipelined phases, no barriers ----
#pragma unroll 1
    for (int p = 0; p < 24; ++p) {
        const ushort_t* ab = w1t + (p * 2) * 512 + colr * 16 + half * 8;
        const short8 A0 = ld8(ab);
        const short8 A1 = ld8(ab + 512);

        if (p < 23) {
            ISSUE_PHASE(p + 1, (p + 1) & 1);
            // keep next phase's 4 DMAs in flight; this phase's DMAs + A-loads drained
            asm volatile("s_waitcnt vmcnt(4)" ::: "memory");
        } else {
            asm volatile("s_waitcnt vmcnt(0)" ::: "memory");
        }
        __builtin_amdgcn_sched_barrier(0);

        const float* xl = &xt[p & 1][wv * 1024 + colr * 32];
#pragma unroll
        for (int s = 0; s < 2; ++s) {
            const int g = s * 4 + half * 2;
            const float4 va = *(const float4*)&xl[((g)     ^ rsw) * 4];
            const float4 vb = *(const float4*)&xl[((g + 1) ^ rsw) * 4];
            const short8 B = mk8(packhi2(va.x, va.y), packhi2(va.z, va.w),
                                 packhi2(vb.x, vb.y), packhi2(vb.z, vb.w));
            acc = MFMA(s == 0 ? A0 : A1, B, acc);
        }
    }

    // ---- tail K-step: cols 768..783 (staged at prologue, drained long ago) ----
    {
        const short8 At = ld8(w1t + 48 * 512 + colr * 16 + half * 8);
        const float* tl = &xtail[wv * 512 + colr * 16];
        const float4 va = ldf4(&tl[(half * 2) * 4]);
        const float4 vb = ldf4(&tl[(half * 2 + 1) * 4]);
        const short8 B = mk8(packhi2(va.x, va.y), packhi2(va.z, va.w),
                             packhi2(vb.x, vb.y), packhi2(vb.z, vb.w));
        acc = MFMA(At, B, acc);
    }

    // ---- bias + relu (pad rows o>=20 get acc=0 from zeroed w1t rows) ----
    float Hv[16];
#pragma unroll
    for (int r = 0; r < 16; ++r) {
        const int o = (r & 3) + 8 * (r >> 2) + 4 * half;
        Hv[r] = fmaxf(acc[r] + b1[o < 20 ? o : 0], 0.f);
    }

    // ---- fc2..fc30: prepacked A hi/lo + bias-in-k, H hi/lo (proven) ----
    const ushort_t* ap = midt + lane * 8;
#pragma unroll 1
    for (int l = 0; l < 29; ++l) {
        const short8 A0h = ld8(ap + l * 2048);
        const short8 A1h = ld8(ap + l * 2048 + 512);
        const short8 A0l = ld8(ap + l * 2048 + 1024);
        const short8 A1l = ld8(ap + l * 2048 + 1536);

        unsigned plo0 = packhi2(Hv[0], Hv[1]), plo1 = packhi2(Hv[2], Hv[3]);
        unsigned phi0 = packhi2(Hv[4], Hv[5]), phi1 = packhi2(Hv[6], Hv[7]);
        plswap(plo0, phi0); plswap(plo1, phi1);
        const short8 B0h = mk8(plo0, plo1, phi0, phi1);

        unsigned qlo0 = packhi2(lopart(Hv[0]), lopart(Hv[1]));
        unsigned qlo1 = packhi2(lopart(Hv[2]), lopart(Hv[3]));
        unsigned qhi0 = packhi2(lopart(Hv[4]), lopart(Hv[5]));
        unsigned qhi1 = packhi2(lopart(Hv[6]), lopart(Hv[7]));
        plswap(qlo0, qhi0); plswap(qlo1, qhi1);
        const short8 B0l = mk8(qlo0, qlo1, qhi0, qhi1);

        const short8 B1h = mk8(half ? 0u : packhi2(Hv[8], Hv[9]),
                               half ? 0u : packhi2(Hv[10], Hv[11]),
                               half ? 0u : 0x00003F80u, 0u);
        const short8 B1l = mk8(half ? 0u : packhi2(lopart(Hv[8]), lopart(Hv[9])),
                               half ? 0u : packhi2(lopart(Hv[10]), lopart(Hv[11])),
                               half ? 0u : 0x3F800000u, 0u);

        f32x16 d;
#pragma unroll
        for (int r = 0; r < 16; ++r) d[r] = 0.f;
        d = MFMA(A0h, B0h, d);
        d = MFMA(A0l, B0h, d);
        d = MFMA(A0h, B0l, d);
        d = MFMA(A1h, B1h, d);
        d = MFMA(A1l, B1h, d);
        d = MFMA(A1h, B1l, d);

        if (l < 28) {
#pragma unroll
            for (int r = 0; r < 16; ++r) Hv[r] = fmaxf(d[r], 0.f);
        } else {
            if (row < nrows) {
#pragma unroll
                for (int r = 0; r < 16; ++r) {
                    const int o = (r & 3) + 8 * (r >> 2) + 4 * half;
                    if (o < 10) out[(size_t)row * 10 + o] = d[r];
                }
            }
        }
    }
#undef ISSUE_PHASE
}

extern "C" void kernel_launch(void* const* d_in, const int* in_sizes, int n_in,
                              void* d_out, int out_size, void* d_ws, size_t ws_size,
                              hipStream_t stream)
{
    const float* x    = (const float*)d_in[0];
    const float* W1   = (const float*)d_in[1];
    const float* b1   = (const float*)d_in[2];
    const float* Wmid = (const float*)d_in[3];
    const float* bmid = (const float*)d_in[4];
    const float* W30  = (const float*)d_in[5];
    const float* b30  = (const float*)d_in[6];
    float* out = (float*)d_out;

    ushort_t* w1t  = (ushort_t*)d_ws;                       // 50176 B
    ushort_t* midt = (ushort_t*)((char*)d_ws + 50176);      // 118784 B

    const int nrows = in_sizes[0] / 784;
    prepack<<<32, 256, 0, stream>>>(W1, Wmid, bmid, W30, b30, w1t, midt);
    const int grid = (nrows + 127) / 128;                   // 512 blocks, 4/CU
    mlp_main<<<grid, 256, 0, stream>>>(x, b1, w1t, midt, out, nrows);
}